// Round 12
// baseline (142.466 us; speedup 1.0000x reference)
//
#include <hip/hip_runtime.h>

// RelativeAttentionPositions: out[b,h,s,t] = dot(tensor[b,h,s,:], E[clip(t-s,-128,128)+128,:]) + bias[h]
// B=4 H=16 S=1024 D=64 MAX_REL=128 VOCAB=257.
// v12 = v8's bf16 c-table (35.8 KB LDS -> 4 blocks/CU = 16 waves/CU, 2x v11) +
// v11's system-scope (sc0 sc1) output stores. Tests whether the sc-store path
// (measured ~4.0 TB/s at 8 waves/CU) scales with per-CU outstanding stores.
//
// c-row layout (u16 bf16, pitch CP=280 = 560 B, 16B-aligned rows), pad = s&7:
//   [0, pad+7] = c0 margin, [pad+8+v] = c[v] (v=0..256), [pad+265, 279] = c256 margin.
// m0 = t0 + (s&7) + 136 - s is always ==0 mod 8 -> 16B-aligned ds_read_b128;
// clamp(m0,0,272) lands fully inside the replicated margins when saturated.

constexpr int S_ = 1024;
constexpr int D_ = 64;
constexpr int BQ = 64;     // rows per block = 4 waves x 16
constexpr int CP = 280;    // u16 pitch (560 B)

typedef __attribute__((ext_vector_type(8))) short short8;   // 8 bf16 (MFMA A/B frag)
typedef __attribute__((ext_vector_type(4))) float f32x4;    // MFMA C/D frag

__device__ __forceinline__ unsigned short f2bf(float x) {
  unsigned u = __float_as_uint(x);
  return (unsigned short)((u + 0x7fffu + ((u >> 16) & 1u)) >> 16);  // RNE
}
__device__ __forceinline__ f32x4 ld4(const float* p) {
  return *reinterpret_cast<const f32x4*>(p);
}
__device__ __forceinline__ short8 pack8(f32x4 a, f32x4 b) {
  short8 r;
  r[0] = (short)f2bf(a.x); r[1] = (short)f2bf(a.y);
  r[2] = (short)f2bf(a.z); r[3] = (short)f2bf(a.w);
  r[4] = (short)f2bf(b.x); r[5] = (short)f2bf(b.y);
  r[6] = (short)f2bf(b.z); r[7] = (short)f2bf(b.w);
  return r;
}
// system-scope store: bypass L2/MALL allocation (sc0 sc1), straight toward HBM.
__device__ __forceinline__ void store_sys(float* __restrict__ base, unsigned byte_off, f32x4 v) {
  asm volatile("global_store_dwordx4 %0, %1, %2 sc0 sc1"
               :: "v"(byte_off), "v"(v), "s"(base)
               : "memory");
}

__global__ __launch_bounds__(256, 4)
void relpos_v12(const float* __restrict__ tensor,
                const float* __restrict__ relk,
                const float* __restrict__ bias,
                float* __restrict__ out) {
  __shared__ __align__(16) unsigned short c_lds[BQ * CP];  // 35840 B -> 4 blocks/CU

  const int tid  = threadIdx.x;
  const int lane = tid & 63;
  const int w    = tid >> 6;
  const int bh   = blockIdx.x >> 4;
  const int s0   = (blockIdx.x & 15) * BQ;
  const int h    = bh & 15;
  const int l15  = lane & 15;
  const int l4   = lane >> 4;
  const int r0   = 16 * w + l4 * 4;     // block-local first row of this lane's D frags
  const int pb   = 4 * (l4 & 1);        // = r0 & 7

  // ---- A fragments: rows s0+16w+l15, k = l4*8 (+0 / +32) ----
  const float* xrow = tensor + ((size_t)(bh * S_ + s0 + 16 * w + l15)) * D_ + l4 * 8;
  short8 a0 = pack8(ld4(xrow),      ld4(xrow + 4));
  short8 a1 = pack8(ld4(xrow + 32), ld4(xrow + 36));
  const float bv = bias[h];

  // ---- compute bf16 c-table with margins (bias baked in) ----
#pragma unroll 2
  for (int nt = 0; nt < 17; ++nt) {
    const int vcol = 16 * nt + l15;
    const int erow = vcol > 256 ? 256 : vcol;
    const float* ep = relk + (size_t)erow * D_ + l4 * 8;
    short8 b0 = pack8(ld4(ep),      ld4(ep + 4));
    short8 b1 = pack8(ld4(ep + 32), ld4(ep + 36));
    f32x4 acc = {0.f, 0.f, 0.f, 0.f};
    acc = __builtin_amdgcn_mfma_f32_16x16x32_bf16(a0, b0, acc, 0, 0, 0);
    acc = __builtin_amdgcn_mfma_f32_16x16x32_bf16(a1, b1, acc, 0, 0, 0);
    // D mapping [m89]: col = l15 (= v-16nt), row = r0 + i
    if (vcol <= 256) {
#pragma unroll
      for (int i = 0; i < 4; ++i)
        c_lds[(r0 + i) * CP + pb + i + 8 + vcol] = f2bf(acc[i] + bv);  // pad = pb+i
    }
    if (l15 == 0 && nt == 0) {          // lane holds c[row][0] -> left margin [0, pad+7]
#pragma unroll
      for (int i = 0; i < 4; ++i) {
        const unsigned short cv = f2bf(acc[i] + bv);
        const int pad = pb + i;
        for (int j = 0; j <= pad + 7; ++j) c_lds[(r0 + i) * CP + j] = cv;
      }
    }
    if (l15 == 0 && nt == 16) {         // lane holds c[row][256] -> right margin [pad+265, 279]
#pragma unroll
      for (int i = 0; i < 4; ++i) {
        const unsigned short cv = f2bf(acc[i] + bv);
        const int pad = pb + i;
        for (int j = pad + 265; j < CP; ++j) c_lds[(r0 + i) * CP + j] = cv;
      }
    }
  }
  __syncthreads();

  // ---- expand: ds_read_b128 (8 c-vals) -> 2 system-scope dwordx4 stores per 32 B ----
  float* obase = out + ((size_t)(bh * S_ + s0)) * (size_t)S_;
  const int mc = 136 - s0;
#pragma unroll 8
  for (int it = 0; it < 32; ++it) {
    const int idx = it * 256 + tid;     // 0..8191 (32-B chunks of the 256 KB region)
    const int rl  = idx >> 7;           // block-local row 0..63
    const int t0  = (idx & 127) << 3;   // 0..1016, step 8
    int m0 = t0 + (rl & 7) + mc - rl;
    m0 = m0 < 0 ? 0 : (m0 > 272 ? 272 : m0);   // stays ==0 mod 8
    const uint4 q = *reinterpret_cast<const uint4*>(&c_lds[rl * CP + m0]);
    f32x4 o0, o1;
    o0.x = __uint_as_float(q.x << 16);
    o0.y = __uint_as_float(q.x & 0xffff0000u);
    o0.z = __uint_as_float(q.y << 16);
    o0.w = __uint_as_float(q.y & 0xffff0000u);
    o1.x = __uint_as_float(q.z << 16);
    o1.y = __uint_as_float(q.z & 0xffff0000u);
    o1.z = __uint_as_float(q.w << 16);
    o1.w = __uint_as_float(q.w & 0xffff0000u);
    store_sys(obase, (unsigned)idx * 32u,       o0);
    store_sys(obase, (unsigned)idx * 32u + 16u, o1);
  }
}

extern "C" void kernel_launch(void* const* d_in, const int* in_sizes, int n_in,
                              void* d_out, int out_size, void* d_ws, size_t ws_size,
                              hipStream_t stream) {
  const float* tensor = (const float*)d_in[0];
  const float* relk   = (const float*)d_in[1];
  // d_in[2] = rel_values_emb (unused in forward), d_in[4] = max_relative_position (=128)
  const float* bias   = (const float*)d_in[3];
  float* out          = (float*)d_out;

  const int B = 4, H = 16;
  dim3 grid(B * H * (S_ / BQ));   // 1024 blocks, 4/CU, 16 waves/CU
  dim3 block(256);
  relpos_v12<<<grid, block, 0, stream>>>(tensor, relk, bias, out);
}

// Round 13
// 70.394 us; speedup vs baseline: 2.0238x; 2.0238x over previous
//
#include <hip/hip_runtime.h>

// RelativeAttentionPositions: out[b,h,s,t] = dot(tensor[b,h,s,:], E[clip(t-s,-128,128)+128,:]) + bias[h]
// B=4 H=16 S=1024 D=64 MAX_REL=128 VOCAB=257.
// v13 = v11's CONTIGUOUS system-scope store pattern (one 16B store per lane per iter,
// wave instruction = dense 1KB — completes every HBM sector; v12 proved strided
// 16B-in-32B sc stores double WRITE_SIZE and collapse to 2.5 TB/s) + bf16 c-table
// (35.3 KB LDS -> 4 blocks/CU = 16 waves/CU, 2x v11's wave count) to test whether
// the sc-store path scales with per-CU outstanding stores (v11: 4.2 TB/s @ 8 waves).
//
// c-row layout (u16 bf16, pitch CP=276 = 552 B, 8B-aligned rows), pad = s&3:
//   [0, pad+3] = c0 margin, [pad+4+v] = c[v] (v=0..256), [pad+261, 275] = c256 margin.
// m0 = t0 + (s&3) + 132 - s is always ==0 mod 4 -> 8B-aligned ds_read_b64;
// clamp(m0,0,264) lands fully inside the replicated margins when saturated.

constexpr int S_ = 1024;
constexpr int D_ = 64;
constexpr int BQ = 64;     // rows per block = 4 waves x 16
constexpr int CP = 276;    // u16 pitch (552 B)

typedef __attribute__((ext_vector_type(8))) short short8;   // 8 bf16 (MFMA A/B frag)
typedef __attribute__((ext_vector_type(4))) float f32x4;    // MFMA C/D frag

__device__ __forceinline__ unsigned short f2bf(float x) {
  unsigned u = __float_as_uint(x);
  return (unsigned short)((u + 0x7fffu + ((u >> 16) & 1u)) >> 16);  // RNE
}
__device__ __forceinline__ f32x4 ld4(const float* p) {
  return *reinterpret_cast<const f32x4*>(p);
}
__device__ __forceinline__ short8 pack8(f32x4 a, f32x4 b) {
  short8 r;
  r[0] = (short)f2bf(a.x); r[1] = (short)f2bf(a.y);
  r[2] = (short)f2bf(a.z); r[3] = (short)f2bf(a.w);
  r[4] = (short)f2bf(b.x); r[5] = (short)f2bf(b.y);
  r[6] = (short)f2bf(b.z); r[7] = (short)f2bf(b.w);
  return r;
}
// system-scope store: bypass L2/MALL allocation (sc0 sc1), straight toward HBM.
__device__ __forceinline__ void store_sys(float* __restrict__ base, unsigned byte_off, f32x4 v) {
  asm volatile("global_store_dwordx4 %0, %1, %2 sc0 sc1"
               :: "v"(byte_off), "v"(v), "s"(base)
               : "memory");
}

__global__ __launch_bounds__(256, 4)
void relpos_v13(const float* __restrict__ tensor,
                const float* __restrict__ relk,
                const float* __restrict__ bias,
                float* __restrict__ out) {
  __shared__ __align__(16) unsigned short c_lds[BQ * CP];  // 35328 B -> 4 blocks/CU

  const int tid  = threadIdx.x;
  const int lane = tid & 63;
  const int w    = tid >> 6;
  const int bh   = blockIdx.x >> 4;
  const int s0   = (blockIdx.x & 15) * BQ;
  const int h    = bh & 15;
  const int l15  = lane & 15;
  const int l4   = lane >> 4;
  const int r0   = 16 * w + l4 * 4;   // first of the 4 block-local rows this lane holds

  // ---- A fragments: rows s0+16w+l15, k = l4*8 (+0 / +32) ----
  const float* xrow = tensor + ((size_t)(bh * S_ + s0 + 16 * w + l15)) * D_ + l4 * 8;
  short8 a0 = pack8(ld4(xrow),      ld4(xrow + 4));
  short8 a1 = pack8(ld4(xrow + 32), ld4(xrow + 36));
  const float bv = bias[h];

  // ---- compute bf16 c-table with margins (bias baked in), pad = s&3 = i ----
#pragma unroll 2
  for (int nt = 0; nt < 17; ++nt) {
    const int vcol = 16 * nt + l15;
    const int erow = vcol > 256 ? 256 : vcol;
    const float* ep = relk + (size_t)erow * D_ + l4 * 8;
    short8 b0 = pack8(ld4(ep),      ld4(ep + 4));
    short8 b1 = pack8(ld4(ep + 32), ld4(ep + 36));
    f32x4 acc = {0.f, 0.f, 0.f, 0.f};
    acc = __builtin_amdgcn_mfma_f32_16x16x32_bf16(a0, b0, acc, 0, 0, 0);
    acc = __builtin_amdgcn_mfma_f32_16x16x32_bf16(a1, b1, acc, 0, 0, 0);
    // D mapping [m89]: col = l15 (= v-16nt), row = r0 + i
    if (vcol <= 256) {
#pragma unroll
      for (int i = 0; i < 4; ++i)
        c_lds[(r0 + i) * CP + i + 4 + vcol] = f2bf(acc[i] + bv);   // pad = (s&3) = i
    }
    if (l15 == 0 && nt == 0) {        // lane holds c[row][0] -> left margin [0, pad+3]
#pragma unroll
      for (int i = 0; i < 4; ++i) {
        const unsigned short cv = f2bf(acc[i] + bv);
        for (int j = 0; j <= i + 3; ++j) c_lds[(r0 + i) * CP + j] = cv;
      }
    }
    if (l15 == 0 && nt == 16) {       // lane holds c[row][256] -> right margin [pad+261, 275]
#pragma unroll
      for (int i = 0; i < 4; ++i) {
        const unsigned short cv = f2bf(acc[i] + bv);
        for (int j = i + 261; j < CP; ++j) c_lds[(r0 + i) * CP + j] = cv;
      }
    }
  }
  __syncthreads();

  // ---- expand: ds_read_b64 -> unpack -> ONE contiguous 16B sc store per lane ----
  float* obase = out + ((size_t)bh * S_ + s0) * (size_t)S_;
  const int mc = 132 - s0;            // m0 = t0 + (rl&3) + 132 - s0 - rl
#pragma unroll 8
  for (int it = 0; it < 64; ++it) {
    const int idx = it * 256 + tid;   // 16-B chunk index within block region (0..16383)
    const int rl  = idx >> 8;         // block-local row 0..63
    const int t0  = (idx & 255) << 2;
    int m0 = t0 + (rl & 3) + mc - rl;
    m0 = m0 < 0 ? 0 : (m0 > 264 ? 264 : m0);   // stays ==0 mod 4
    const uint2 q = *reinterpret_cast<const uint2*>(&c_lds[rl * CP + m0]);
    f32x4 o;
    o.x = __uint_as_float(q.x << 16);
    o.y = __uint_as_float(q.x & 0xffff0000u);
    o.z = __uint_as_float(q.y << 16);
    o.w = __uint_as_float(q.y & 0xffff0000u);
    store_sys(obase, (unsigned)idx * 16u, o);
  }
}

extern "C" void kernel_launch(void* const* d_in, const int* in_sizes, int n_in,
                              void* d_out, int out_size, void* d_ws, size_t ws_size,
                              hipStream_t stream) {
  const float* tensor = (const float*)d_in[0];
  const float* relk   = (const float*)d_in[1];
  // d_in[2] = rel_values_emb (unused in forward), d_in[4] = max_relative_position (=128)
  const float* bias   = (const float*)d_in[3];
  float* out          = (float*)d_out;

  const int B = 4, H = 16;
  dim3 grid(B * H * (S_ / BQ));   // 1024 blocks, 4/CU, 16 waves/CU
  dim3 block(256);
  relpos_v13<<<grid, block, 0, stream>>>(tensor, relk, bias, out);
}